// Round 7
// baseline (71.048 us; speedup 1.0000x reference)
//
#include <hip/hip_runtime.h>

// QKV attention, N=4 H=8 D=64 T=2048, fp32 in/out, bf16 MFMA internally.
// R7: LDS-bandwidth diet. R6 analysis: ~28 KB LDS traffic per wave-iter ->
// ~60% LDS-unit occupancy at 8 waves/CU = the coupling bottleneck.
// Change: eliminate the Ps LDS round-trip. After swapped QK^T, lane (g,l15)
// holds P^T[s=ss*16+g*4+r][t=l15] = EXACTLY the B-fragment layout of
// v_mfma_f32_16x16x16_bf16 (col=l15, k=g*4+j). PV consumes P directly from
// registers via k=16 MFMAs (4 ss steps); V A-frags become b64 reads.
// LDS/wave-iter: 28 KB -> 20 KB; S->PV chain loses pack/ds_write/ds_read.

typedef __bf16 bf8v __attribute__((ext_vector_type(8)));
typedef __bf16 bf4 __attribute__((ext_vector_type(4)));
typedef short s4 __attribute__((ext_vector_type(4)));
typedef float f4 __attribute__((ext_vector_type(4)));
typedef int i4 __attribute__((ext_vector_type(4)));

#define SEQ 2048
#define DD 64
#define NHEADS 32
#define QBLK 128
#define SBLK 64
#define NTILES (SEQ / SBLK)
#define TILEK (SBLK * DD)    // elements per K/V tile (4096)
#define NTHR 256

// scale = 1/sqrt(sqrt(64)) on both q and k; log2(e) folded into q's side
#define KSC 0.35355339059327373f
#define QSC (0.35355339059327373f * 1.4426950408889634f)

#if __has_builtin(__builtin_amdgcn_exp2f)
#define EXP2(x) __builtin_amdgcn_exp2f(x)
#else
#define EXP2(x) exp2f(x)
#endif

__device__ __forceinline__ void gload16(i4& dst, const __bf16* p) {
    asm volatile("global_load_dwordx4 %0, %1, off" : "=&v"(dst) : "v"(p));
}

// drain all vmem; "memory" clobber pins the following LDS writes below it
#define VMWAIT0() do { asm volatile("s_waitcnt vmcnt(0)" ::: "memory"); \
                       __builtin_amdgcn_sched_barrier(0); } while (0)
#define SBAR() __builtin_amdgcn_sched_barrier(0)

// PV matrix op: D = A(16x16 bf16) * B(16x16 bf16) + C, k=16.
// A: row=l15, k=g*4+j ; B: col=l15, k=g*4+j ; C/D: col=l15, row=g*4+reg.
#if __has_builtin(__builtin_amdgcn_mfma_f32_16x16x16bf16_1k)
__device__ __forceinline__ f4 mfma16(bf4 a, bf4 b, f4 c) {
    union U { bf4 v; s4 s; };
    U ua; ua.v = a;
    U ub; ub.v = b;
    return __builtin_amdgcn_mfma_f32_16x16x16bf16_1k(ua.s, ub.s, c, 0, 0, 0);
}
#else
__device__ __forceinline__ f4 mfma16(bf4 a, bf4 b, f4 c) {
    asm("v_mfma_f32_16x16x16_bf16 %0, %1, %2, %0" : "+v"(c) : "v"(a), "v"(b));
    return c;
}
#endif

// ---------------- prep: fp32 -> bf16, K transposed+scaled, V straight --------
__global__ void prep_kernel(const float* __restrict__ qkv,
                            __bf16* __restrict__ KT, __bf16* __restrict__ Vb) {
    const int bx = blockIdx.x, tid = threadIdx.x;
    if (bx < 256) {
        const int head = bx >> 3, sblk = bx & 7;
        const int b = head >> 3, h = head & 7;
        const float* kp = qkv + (size_t)(b * 1536 + 512 + h * 64) * SEQ;
        __bf16* dst = KT + (size_t)head * SEQ * DD;
        const int s = sblk * 256 + tid;
#pragma unroll
        for (int c0 = 0; c0 < DD; c0 += 8) {
            bf8v v;
#pragma unroll
            for (int j = 0; j < 8; ++j)
                v[j] = (__bf16)(kp[(size_t)(c0 + j) * SEQ + s] * KSC);
            *(bf8v*)(dst + (size_t)s * DD + c0) = v;
        }
    } else {
        const int job = bx - 256;
        const int head = job >> 4, part = job & 15;
        const int b = head >> 3, h = head & 7;
        const float* vp = qkv + (size_t)(b * 1536 + 1024 + h * 64) * SEQ;
        __bf16* dst = Vb + (size_t)head * DD * SEQ;
#pragma unroll
        for (int i = 0; i < 4; ++i) {
            const int e = part * 8192 + (i * 256 + tid) * 8;
            const float4* f = (const float4*)(vp + e);
            float4 a = f[0], c = f[1];
            bf8v o;
            o[0] = (__bf16)a.x; o[1] = (__bf16)a.y; o[2] = (__bf16)a.z; o[3] = (__bf16)a.w;
            o[4] = (__bf16)c.x; o[5] = (__bf16)c.y; o[6] = (__bf16)c.z; o[7] = (__bf16)c.w;
            *(bf8v*)(dst + e) = o;
        }
    }
}

// swizzled LDS reads: rows are 64 elem (128 B); 16B chunk stored at pos c16^(r&7)
__device__ __forceinline__ bf8v ldswz(const __bf16* base, int r, int c16) {
    return *(const bf8v*)(base + r * DD + (((c16) ^ (r & 7)) << 3));
}
__device__ __forceinline__ bf4 ldswz4(const __bf16* base, int r, int sloc) {
    const int c16 = sloc >> 3, off = sloc & 7;
    return *(const bf4*)(base + r * DD + (((c16) ^ (r & 7)) << 3) + off);
}

__global__ __launch_bounds__(NTHR, 2) void attn_kernel(
    const float* __restrict__ qkv, const __bf16* __restrict__ KT,
    const __bf16* __restrict__ Vb, float* __restrict__ out)
{
    __shared__ __bf16 KL[2][TILEK];    // K tile, rows = s-local, swizzled
    __shared__ __bf16 VL[2][TILEK];    // V tile, rows = c,       swizzled

    const int tid = threadIdx.x;
    const int wid = tid >> 6;
    const int lane = tid & 63;
    const int g = lane >> 4;
    const int l15 = lane & 15;

    // XCD-bijective swizzle: 512 blocks, 8 XCDs -> 64-block chunks = 4 heads/XCD
    const int bid = blockIdx.x;
    const int bx = (bid & 7) * 64 + (bid >> 3);
    const int head = bx >> 4;
    const int t0 = (bx & 15) * QBLK;
    const int b = head >> 3, h = head & 7;

    const float* qp = qkv + (size_t)(b * 1536 + h * 64) * SEQ;
    const __bf16* kt = KT + (size_t)head * SEQ * DD;
    const __bf16* vb = Vb + (size_t)head * DD * SEQ;
    float* op = out + (size_t)head * DD * SEQ;

    // ---- staging geometry: thread covers rows sr and sr+32, LDS pos sp ----
    const int sp  = tid & 7;           // 16B-chunk position within row
    const int sr  = tid >> 3;          // 0..31
    const int scs = sp ^ (sr & 7);     // source chunk (involution; same for sr+32)
    const __bf16* kg0 = kt + sr * DD + (scs << 3);
    const __bf16* kg1 = kt + (sr + 32) * DD + (scs << 3);
    const __bf16* vg0 = vb + (size_t)sr * SEQ + (scs << 3);
    const __bf16* vg1 = vb + (size_t)(sr + 32) * SEQ + (scs << 3);
    const int l0 = sr * DD + (sp << 3);
    const int l1 = (sr + 32) * DD + (sp << 3);

    i4 rk0, rk1, rv0, rv1;

    // ---- prologue: issue tile-0 loads; Q conversion overlaps their flight ----
    SBAR();
    gload16(rk0, kg0);
    gload16(rk1, kg1);
    gload16(rv0, vg0);
    gload16(rv1, vg1);
    SBAR();

    // Q fragments (one-time fp32 loads + convert, scaled by QSC)
    bf8v qf[2][2];
    {
        const int tq = t0 + wid * 32 + l15;
#pragma unroll
        for (int ts = 0; ts < 2; ++ts)
#pragma unroll
            for (int ks = 0; ks < 2; ++ks) {
                bf8v q;
#pragma unroll
                for (int j = 0; j < 8; ++j)
                    q[j] = (__bf16)(qp[(size_t)(ks * 32 + g * 8 + j) * SEQ + tq + ts * 16] * QSC);
                qf[ts][ks] = q;
            }
    }

    f4 Oacc[4][2];
#pragma unroll
    for (int ms = 0; ms < 4; ++ms) {
        Oacc[ms][0] = (f4){0.f, 0.f, 0.f, 0.f};
        Oacc[ms][1] = (f4){0.f, 0.f, 0.f, 0.f};
    }
    float lper[2] = {0.f, 0.f};   // per-lane softmax-sum partials (reduced in epilogue)

    VMWAIT0();
    *(i4*)&KL[0][l0] = rk0;  *(i4*)&KL[0][l1] = rk1;
    *(i4*)&VL[0][l0] = rv0;  *(i4*)&VL[0][l1] = rv1;
    __syncthreads();

    // ---- main loop ----
    for (int it = 0; it < NTILES; ++it) {
        const int cb = it & 1;
        const __bf16* kcu = KL[cb];
        const __bf16* vcu = VL[cb];
        const bool more = (it + 1 < NTILES);

        // pinned issue of tile(it+1) loads; latency hides under QK^T + softmax
        if (more) {
            const int nx = it + 1;
            SBAR();
            gload16(rk0, kg0 + nx * TILEK);
            gload16(rk1, kg1 + nx * TILEK);
            gload16(rv0, vg0 + nx * SBLK);
            gload16(rv1, vg1 + nx * SBLK);
            SBAR();
        }

        // ---- QK^T (swapped): S^T[s][t] = sum_c K[s][c] Q[c][t] ----
        f4 S[4][2];
#pragma unroll
        for (int ss = 0; ss < 4; ++ss) {
            S[ss][0] = (f4){0.f, 0.f, 0.f, 0.f};
            S[ss][1] = (f4){0.f, 0.f, 0.f, 0.f};
        }
        __builtin_amdgcn_s_setprio(1);
#pragma unroll
        for (int ks = 0; ks < 2; ++ks)
#pragma unroll
            for (int ss = 0; ss < 4; ++ss) {
                bf8v a = ldswz(kcu, ss * 16 + l15, ks * 4 + g);
                S[ss][0] = __builtin_amdgcn_mfma_f32_16x16x32_bf16(a, qf[0][ks], S[ss][0], 0, 0, 0);
                S[ss][1] = __builtin_amdgcn_mfma_f32_16x16x32_bf16(a, qf[1][ks], S[ss][1], 0, 0, 0);
            }
        __builtin_amdgcn_s_setprio(0);

        // ---- V A-fragments for k=16 PV: V[ms*16+l15][ss*16+g*4 .. +3] ----
        bf4 vf[4][4];   // [ms][ss]
#pragma unroll
        for (int ms = 0; ms < 4; ++ms)
#pragma unroll
            for (int ss = 0; ss < 4; ++ss)
                vf[ms][ss] = ldswz4(vcu, ms * 16 + l15, ss * 16 + g * 4);

        // ---- softmax (no max-subtract; P = 2^S; sum kept per-lane).
        // P stays in registers: pb[ts][ss] IS the PV B-fragment.
        bf4 pb[2][4];
#pragma unroll
        for (int ts = 0; ts < 2; ++ts) {
            float tsum = 0.f;
#pragma unroll
            for (int ss = 0; ss < 4; ++ss) {
                bf4 q;
#pragma unroll
                for (int r = 0; r < 4; ++r) {
                    float e = EXP2(S[ss][ts][r]);
                    tsum += e;
                    q[r] = (__bf16)e;
                }
                pb[ts][ss] = q;
            }
            lper[ts] += tsum;
        }

        // ---- mid-iteration sync: land tile(it+1), publish to buf^1, barrier.
        // Race-safe: reads of a buffer and its next write are separated by
        // exactly one barrier (PV below is register-only).
        if (more) {
            VMWAIT0();
            __bf16* kn = (__bf16*)KL[cb ^ 1];
            __bf16* vn = (__bf16*)VL[cb ^ 1];
            *(i4*)&kn[l0] = rk0;  *(i4*)&kn[l1] = rk1;
            *(i4*)&vn[l0] = rv0;  *(i4*)&vn[l1] = rv1;
            __syncthreads();
        }

        // ---- PV: O[c][t] += V[c][s] P^T[s][t], all operands in registers ----
        __builtin_amdgcn_s_setprio(1);
#pragma unroll
        for (int ss = 0; ss < 4; ++ss)
#pragma unroll
            for (int ms = 0; ms < 4; ++ms) {
                Oacc[ms][0] = mfma16(vf[ms][ss], pb[0][ss], Oacc[ms][0]);
                Oacc[ms][1] = mfma16(vf[ms][ss], pb[1][ss], Oacc[ms][1]);
            }
        __builtin_amdgcn_s_setprio(0);
    }

    // hazard guard for asm-mfma path (MFMA write -> VALU read of Oacc)
    asm volatile("s_nop 7\n\ts_nop 7" :::);

    // ---- epilogue: one cross-lane reduce of the softmax sums, normalize, store
#pragma unroll
    for (int ts = 0; ts < 2; ++ts) {
        float l = lper[ts];
        l += __shfl_xor(l, 16);
        l += __shfl_xor(l, 32);
        const float rl = 1.0f / l;
        const int t = t0 + wid * 32 + ts * 16 + l15;
#pragma unroll
        for (int ms = 0; ms < 4; ++ms)
#pragma unroll
            for (int r = 0; r < 4; ++r)
                op[(size_t)(ms * 16 + g * 4 + r) * SEQ + t] = Oacc[ms][ts][r] * rl;
    }
}

extern "C" void kernel_launch(void* const* d_in, const int* in_sizes, int n_in,
                              void* d_out, int out_size, void* d_ws, size_t ws_size,
                              hipStream_t stream) {
    const float* qkv = (const float*)d_in[0];
    float* out = (float*)d_out;
    __bf16* KT = (__bf16*)d_ws;                         // [32][2048][64] bf16
    __bf16* Vb = KT + (size_t)NHEADS * SEQ * DD;        // [32][64][2048] bf16
    prep_kernel<<<dim3(256 + 512), dim3(NTHR), 0, stream>>>(qkv, KT, Vb);
    attn_kernel<<<dim3(NHEADS * (SEQ / QBLK)), dim3(NTHR), 0, stream>>>(qkv, KT, Vb, out);
}

// Round 8
// 64.759 us; speedup vs baseline: 1.0971x; 1.0971x over previous
//
#include <hip/hip_runtime.h>

// QKV attention, N=4 H=8 D=64 T=2048, fp32 in/out, bf16 MFMA internally.
// R8: 32x32x16 restructure (m214/T12 route). Swapped QK^T at 32x32 puts
// S^T rows s=(reg&3)+8*(reg>>2)+4*hi in-lane; the PV B-frag (k=8*hi+j) then
// needs ONLY a hi-half exchange = v_permlane32_swap_b32 (VALU). P never
// touches LDS; PV stays at full-K MFMAs (8 per iter, same FLOP/issue as QK).
// LDS ops/wave-iter 44 -> 20; Ps buffer freed (LDS 50KB -> 32KB).
// Keeps R5/R6 skeleton: reg-staged double-buffered LDS K/V, XOR swizzle,
// pinned gloads, one vmcnt(0)+barrier per tile, XCD swizzle, setprio.

typedef __bf16 bf8v __attribute__((ext_vector_type(8)));
typedef float f16v __attribute__((ext_vector_type(16)));
typedef int i4 __attribute__((ext_vector_type(4)));

#define SEQ 2048
#define DD 64
#define NHEADS 32
#define QBLK 128
#define SBLK 64
#define NTILES (SEQ / SBLK)
#define TILEK (SBLK * DD)    // elements per K/V tile (4096)
#define NTHR 256

// scale = 1/sqrt(sqrt(64)) on both q and k; log2(e) folded into q's side
#define KSC 0.35355339059327373f
#define QSC (0.35355339059327373f * 1.4426950408889634f)

#if __has_builtin(__builtin_amdgcn_exp2f)
#define EXP2(x) __builtin_amdgcn_exp2f(x)
#else
#define EXP2(x) exp2f(x)
#endif

__device__ __forceinline__ void gload16(i4& dst, const __bf16* p) {
    asm volatile("global_load_dwordx4 %0, %1, off" : "=&v"(dst) : "v"(p));
}

// drain all vmem; "memory" clobber pins the following LDS writes below it
#define VMWAIT0() do { asm volatile("s_waitcnt vmcnt(0)" ::: "memory"); \
                       __builtin_amdgcn_sched_barrier(0); } while (0)
#define SBAR() __builtin_amdgcn_sched_barrier(0)

// hi-half lane exchange: after the op, a = {a_lo, b_lo-from-partner},
// b = {a_hi-from-partner, b_hi}  (vdst hi <-> vsrc lo swap)
#if __has_builtin(__builtin_amdgcn_permlane32_swap)
typedef int i2v __attribute__((ext_vector_type(2)));
__device__ __forceinline__ void plswap(unsigned& a, unsigned& b) {
    i2v r = __builtin_amdgcn_permlane32_swap((int)a, (int)b, false, false);
    a = (unsigned)r.x;
    b = (unsigned)r.y;
}
#else
__device__ __forceinline__ void plswap(unsigned& a, unsigned& b) {
    asm volatile("v_permlane32_swap_b32 %0, %1" : "+v"(a), "+v"(b));
}
#endif

// ---------------- prep: fp32 -> bf16, K transposed+scaled, V straight --------
__global__ void prep_kernel(const float* __restrict__ qkv,
                            __bf16* __restrict__ KT, __bf16* __restrict__ Vb) {
    const int bx = blockIdx.x, tid = threadIdx.x;
    if (bx < 256) {
        const int head = bx >> 3, sblk = bx & 7;
        const int b = head >> 3, h = head & 7;
        const float* kp = qkv + (size_t)(b * 1536 + 512 + h * 64) * SEQ;
        __bf16* dst = KT + (size_t)head * SEQ * DD;
        const int s = sblk * 256 + tid;
#pragma unroll
        for (int c0 = 0; c0 < DD; c0 += 8) {
            bf8v v;
#pragma unroll
            for (int j = 0; j < 8; ++j)
                v[j] = (__bf16)(kp[(size_t)(c0 + j) * SEQ + s] * KSC);
            *(bf8v*)(dst + (size_t)s * DD + c0) = v;
        }
    } else {
        const int job = bx - 256;
        const int head = job >> 4, part = job & 15;
        const int b = head >> 3, h = head & 7;
        const float* vp = qkv + (size_t)(b * 1536 + 1024 + h * 64) * SEQ;
        __bf16* dst = Vb + (size_t)head * DD * SEQ;
#pragma unroll
        for (int i = 0; i < 4; ++i) {
            const int e = part * 8192 + (i * 256 + tid) * 8;
            const float4* f = (const float4*)(vp + e);
            float4 a = f[0], c = f[1];
            bf8v o;
            o[0] = (__bf16)a.x; o[1] = (__bf16)a.y; o[2] = (__bf16)a.z; o[3] = (__bf16)a.w;
            o[4] = (__bf16)c.x; o[5] = (__bf16)c.y; o[6] = (__bf16)c.z; o[7] = (__bf16)c.w;
            *(bf8v*)(dst + e) = o;
        }
    }
}

// swizzled LDS fragment read: row r (64 elem = 128 B rows), 16B chunk c16
// stored at position c16 ^ (r & 7)
__device__ __forceinline__ bf8v ldswz(const __bf16* base, int r, int c16) {
    return *(const bf8v*)(base + r * DD + (((c16) ^ (r & 7)) << 3));
}

__global__ __launch_bounds__(NTHR, 2) void attn_kernel(
    const float* __restrict__ qkv, const __bf16* __restrict__ KT,
    const __bf16* __restrict__ Vb, float* __restrict__ out)
{
    __shared__ __bf16 KL[2][TILEK];    // K tile, rows = s-local, swizzled
    __shared__ __bf16 VL[2][TILEK];    // V tile, rows = c,       swizzled

    const int tid = threadIdx.x;
    const int wid = tid >> 6;
    const int lane = tid & 63;
    const int hi = lane >> 5;
    const int l31 = lane & 31;

    // XCD-bijective swizzle: 512 blocks, 8 XCDs -> 64-block chunks = 4 heads/XCD
    const int bid = blockIdx.x;
    const int bx = (bid & 7) * 64 + (bid >> 3);
    const int head = bx >> 4;
    const int t0 = (bx & 15) * QBLK;
    const int b = head >> 3, h = head & 7;

    const float* qp = qkv + (size_t)(b * 1536 + h * 64) * SEQ;
    const __bf16* kt = KT + (size_t)head * SEQ * DD;
    const __bf16* vb = Vb + (size_t)head * DD * SEQ;
    float* op = out + (size_t)head * DD * SEQ;

    // ---- staging geometry: thread covers rows sr and sr+32, LDS pos sp ----
    const int sp  = tid & 7;           // 16B-chunk position within row
    const int sr  = tid >> 3;          // 0..31
    const int scs = sp ^ (sr & 7);     // source chunk (involution; same for sr+32)
    const __bf16* kg0 = kt + sr * DD + (scs << 3);
    const __bf16* kg1 = kt + (sr + 32) * DD + (scs << 3);
    const __bf16* vg0 = vb + (size_t)sr * SEQ + (scs << 3);
    const __bf16* vg1 = vb + (size_t)(sr + 32) * SEQ + (scs << 3);
    const int l0 = sr * DD + (sp << 3);
    const int l1 = (sr + 32) * DD + (sp << 3);

    i4 rk0, rk1, rv0, rv1;

    // ---- prologue: issue tile-0 loads; Q conversion overlaps their flight ----
    SBAR();
    gload16(rk0, kg0);
    gload16(rk1, kg1);
    gload16(rv0, vg0);
    gload16(rv1, vg1);
    SBAR();

    // Q B-fragments for 32x32x16: col = t = l31, k = c = kb*16 + hi*8 + j
    const int tq = t0 + wid * 32 + l31;
    bf8v qf[4];
#pragma unroll
    for (int kb = 0; kb < 4; ++kb) {
        bf8v q;
#pragma unroll
        for (int j = 0; j < 8; ++j)
            q[j] = (__bf16)(qp[(size_t)(kb * 16 + hi * 8 + j) * SEQ + tq] * QSC);
        qf[kb] = q;
    }

    f16v Oacc[2];
    Oacc[0] = (f16v)0.0f;
    Oacc[1] = (f16v)0.0f;
    float lp[4] = {0.f, 0.f, 0.f, 0.f};   // per-lane softmax-sum partials

    VMWAIT0();
    *(i4*)&KL[0][l0] = rk0;  *(i4*)&KL[0][l1] = rk1;
    *(i4*)&VL[0][l0] = rv0;  *(i4*)&VL[0][l1] = rv1;
    __syncthreads();

    // ---- main loop ----
    for (int it = 0; it < NTILES; ++it) {
        const int cb = it & 1;
        const __bf16* kcu = KL[cb];
        const __bf16* vcu = VL[cb];
        const bool more = (it + 1 < NTILES);

        // pinned issue of tile(it+1) loads; latency hides under QK^T + softmax
        if (more) {
            const int nx = it + 1;
            SBAR();
            gload16(rk0, kg0 + nx * TILEK);
            gload16(rk1, kg1 + nx * TILEK);
            gload16(rv0, vg0 + nx * SBLK);
            gload16(rv1, vg1 + nx * SBLK);
            SBAR();
        }

        // ---- QK^T (swapped, 32x32x16): S^T[s][t], s = sb*32+(reg&3)+8(reg>>2)+4hi
        bf8v ka[2][4];
#pragma unroll
        for (int sb = 0; sb < 2; ++sb)
#pragma unroll
            for (int kb = 0; kb < 4; ++kb)
                ka[sb][kb] = ldswz(kcu, sb * 32 + l31, 2 * kb + hi);

        f16v S[2];
        S[0] = (f16v)0.0f;
        S[1] = (f16v)0.0f;
        __builtin_amdgcn_s_setprio(1);
#pragma unroll
        for (int kb = 0; kb < 4; ++kb) {
            S[0] = __builtin_amdgcn_mfma_f32_32x32x16_bf16(ka[0][kb], qf[kb], S[0], 0, 0, 0);
            S[1] = __builtin_amdgcn_mfma_f32_32x32x16_bf16(ka[1][kb], qf[kb], S[1], 0, 0, 0);
        }
        __builtin_amdgcn_s_setprio(0);

        // ---- V A-fragments (depend only on barrier; latency under softmax) ----
        bf8v vf[2][4];   // [c-block][kb]
#pragma unroll
        for (int vcb = 0; vcb < 2; ++vcb)
#pragma unroll
            for (int kb = 0; kb < 4; ++kb)
                vf[vcb][kb] = ldswz(vcu, vcb * 32 + l31, 2 * kb + hi);

        // ---- softmax (no max-subtract; P = 2^S; sums per-lane, 4 chains) ----
        // run q = regs 4q..4q+3 -> s = sb*32 + 8q + 4hi + {0..3}; pack to 2 dwords
        unsigned pd[2][4][2];
#pragma unroll
        for (int sb = 0; sb < 2; ++sb)
#pragma unroll
            for (int q = 0; q < 4; ++q) {
                float e0 = EXP2(S[sb][4 * q + 0]);
                float e1 = EXP2(S[sb][4 * q + 1]);
                float e2 = EXP2(S[sb][4 * q + 2]);
                float e3 = EXP2(S[sb][4 * q + 3]);
                lp[q] += (e0 + e1) + (e2 + e3);
                union { __bf16 h[2]; unsigned u; } p0, p1;
                p0.h[0] = (__bf16)e0; p0.h[1] = (__bf16)e1;
                p1.h[0] = (__bf16)e2; p1.h[1] = (__bf16)e3;
                pd[sb][q][0] = p0.u;
                pd[sb][q][1] = p1.u;
            }

        // ---- build PV B-frags in-register: hi-half exchange via permlane32_swap.
        // After swap(run2m.dw, run2m+1.dw): B[kb=2sb+m] = {r2m.d0, r2m.d1, r2m+1.d0, r2m+1.d1}
#pragma unroll
        for (int sb = 0; sb < 2; ++sb)
#pragma unroll
            for (int m = 0; m < 2; ++m) {
                plswap(pd[sb][2 * m][0], pd[sb][2 * m + 1][0]);
                plswap(pd[sb][2 * m][1], pd[sb][2 * m + 1][1]);
            }

        // ---- mid-iteration sync: land tile(it+1), publish to buf^1, barrier.
        // Race-safe: PV below is register-only; next-iter reads are behind this barrier.
        if (more) {
            VMWAIT0();
            __bf16* kn = (__bf16*)KL[cb ^ 1];
            __bf16* vn = (__bf16*)VL[cb ^ 1];
            *(i4*)&kn[l0] = rk0;  *(i4*)&kn[l1] = rk1;
            *(i4*)&vn[l0] = rv0;  *(i4*)&vn[l1] = rv1;
            __syncthreads();
        }

        // VALU(permlane)->MFMA-read hazard guard for the no-barrier last iter
        asm volatile("s_nop 2" :::);

        // ---- PV: O[c][t] += V[c][s] P^T[s][t], all operands in registers ----
        __builtin_amdgcn_s_setprio(1);
#pragma unroll
        for (int sb = 0; sb < 2; ++sb)
#pragma unroll
            for (int m = 0; m < 2; ++m) {
                const int kb = 2 * sb + m;
                union { unsigned u[4]; bf8v b; } f;
                f.u[0] = pd[sb][2 * m][0];
                f.u[1] = pd[sb][2 * m][1];
                f.u[2] = pd[sb][2 * m + 1][0];
                f.u[3] = pd[sb][2 * m + 1][1];
                Oacc[0] = __builtin_amdgcn_mfma_f32_32x32x16_bf16(vf[0][kb], f.b, Oacc[0], 0, 0, 0);
                Oacc[1] = __builtin_amdgcn_mfma_f32_32x32x16_bf16(vf[1][kb], f.b, Oacc[1], 0, 0, 0);
            }
        __builtin_amdgcn_s_setprio(0);
    }

    // ---- epilogue: fold partials, one hi-half shfl, normalize, store fp32 ----
    float l = (lp[0] + lp[1]) + (lp[2] + lp[3]);
    l += __shfl_xor(l, 32);
    const float rl = 1.0f / l;
#pragma unroll
    for (int cbk = 0; cbk < 2; ++cbk)
#pragma unroll
        for (int r = 0; r < 16; ++r) {
            const int row = cbk * 32 + (r & 3) + 8 * (r >> 2) + 4 * hi;
            op[(size_t)row * SEQ + tq] = Oacc[cbk][r] * rl;
        }
}

extern "C" void kernel_launch(void* const* d_in, const int* in_sizes, int n_in,
                              void* d_out, int out_size, void* d_ws, size_t ws_size,
                              hipStream_t stream) {
    const float* qkv = (const float*)d_in[0];
    float* out = (float*)d_out;
    __bf16* KT = (__bf16*)d_ws;                         // [32][2048][64] bf16
    __bf16* Vb = KT + (size_t)NHEADS * SEQ * DD;        // [32][64][2048] bf16
    prep_kernel<<<dim3(256 + 512), dim3(NTHR), 0, stream>>>(qkv, KT, Vb);
    attn_kernel<<<dim3(NHEADS * (SEQ / QBLK)), dim3(NTHR), 0, stream>>>(qkv, KT, Vb, out);
}